// Round 1
// baseline (223.930 us; speedup 1.0000x reference)
//
#include <hip/hip_runtime.h>
#include <math.h>

// Problem constants (from reference setup_inputs): B=16, C=1, H=1024, W=1024
#define IMG_H 1024
#define IMG_W 1024
#define NB    16
#define NROWS (NB * IMG_H)        // 16384 flat rows
#define WPR   (IMG_W / 32)        // 32 u32 words per row
#define NTOTAL 16777216.0
#define NBUCKET 1024
#define LN2 0.6931471805599453

struct Acc {
    double s2A, s2E, s2M;         // sums of log2(pSel) over: all px, edge px, mask px
    unsigned int cMask, cEdge;    // counts of label==1 and edge==1
};                                 // 32 bytes = 8 dwords

// ---------------- Kernel 1: bitpack label only (no dilation) ----------------
// Each block: 8 consecutive flat rows (8192 px), 256 threads, int4 loads.
// Also zeroes the Acc buckets + done counter (replacing a memset launch).
// Dilation is fully deferred to k_bce (separable OR: vertical then horizontal).
__global__ void k_pack(const int* __restrict__ label,
                       unsigned int* __restrict__ maskbits,
                       Acc* __restrict__ acc,
                       unsigned int* __restrict__ done) {
    __shared__ unsigned int lm[256];          // 8 rows * 32 words
    const int t = threadIdx.x;
    const long rowBase = (long)blockIdx.x * 8;

    if (blockIdx.x < NBUCKET && t < 8)        // zero this block's bucket
        ((unsigned int*)&acc[blockIdx.x])[t] = 0u;
    if (blockIdx.x == 0 && t == 8)            // zero the last-block counter
        *done = 0u;

    // Bitpack: each thread loads 8 int4 (32 labels); nibble -> word via 3 shfl_xor.
    const int4* L = (const int4*)(label + rowBase * IMG_W);
    #pragma unroll
    for (int k = 0; k < 8; ++k) {
        const int fi = k * 256 + t;           // int4 index in tile, 0..2047
        const int4 v = L[fi];
        unsigned int wbits = ((unsigned int)(v.x & 1)
                           | ((unsigned int)(v.y & 1) << 1)
                           | ((unsigned int)(v.z & 1) << 2)
                           | ((unsigned int)(v.w & 1) << 3)) << ((t & 7) * 4);
        wbits |= __shfl_xor(wbits, 1);
        wbits |= __shfl_xor(wbits, 2);
        wbits |= __shfl_xor(wbits, 4);
        if ((t & 7) == 0) lm[fi >> 3] = wbits;
    }
    __syncthreads();
    maskbits[rowBase * WPR + t] = lm[t];      // coalesced 1 KiB/block
}

// ---------------- Kernel 2: dilate (V then H) + classified BCE + finalize ---
// 2048 blocks x 256 threads; each block = 8 rows (8192 px), 32 px/thread.
__global__ void k_bce(const float* __restrict__ pred,
                      const unsigned int* __restrict__ maskbits,
                      Acc* __restrict__ acc,
                      unsigned int* __restrict__ done,
                      float* __restrict__ out) {
    __shared__ unsigned int vE[256];          // vertically-ORed words
    __shared__ unsigned int eE[256];          // final edge words (V+H dilated)
    __shared__ unsigned int eM[256];          // raw mask words (own rows)
    __shared__ float redf[12];                // 4 waves * 3 sums
    __shared__ unsigned int redc[8];          // 4 waves * 2 counts
    __shared__ double redd[12];
    __shared__ double redn[8];
    __shared__ int lastFlag;

    const int t  = threadIdx.x;
    const int R0 = blockIdx.x * 8;            // first flat row of tile
    const int b  = R0 >> 10;                  // image index
    const int i0 = R0 & 1023;                 // first row within image
    const int g = t >> 5, w = t & 31;         // row-in-tile, word

    // Vertical 15-tap OR on raw mask bits: one word per thread.
    {
        const int i = i0 + g;
        int lo = i - 7; if (lo < 0) lo = 0;
        int hi = i + 7; if (hi > 1023) hi = 1023;
        const unsigned int* base = maskbits + ((long)b << 10) * WPR + w;
        unsigned int e = 0u;
        for (int ri = lo; ri <= hi; ++ri) e |= base[(long)ri * WPR];
        vE[t] = e;
        eM[t] = base[(long)i * WPR];          // own-row raw mask (L2 hit)
    }
    __syncthreads();

    // Horizontal 15-tap OR within the row using LDS neighbors.
    unsigned int cE;
    {
        unsigned int prev = w        ? vE[t - 1] : 0u;
        unsigned int cur  =            vE[t];
        unsigned int next = (w < 31) ? vE[t + 1] : 0u;
        unsigned long long Wn = (((unsigned long long)prev) >> 16)
                              | (((unsigned long long)cur)  << 16)
                              | (((unsigned long long)next) << 48);
        unsigned long long a = Wn;
        #pragma unroll
        for (int d = 1; d <= 7; ++d) a |= (Wn >> d) | (Wn << d);
        unsigned int ew = (unsigned int)(a >> 16);
        eE[t] = ew;
        cE = __popc(ew);
    }
    unsigned int cM = __popc(eM[t]);
    __syncthreads();

    // 32 px/thread via 8 coalesced float4 loads; accumulate log2 sums.
    float s2A = 0.f, s2E = 0.f, s2M = 0.f;
    const float4* p4 = (const float4*)(pred + (long)R0 * IMG_W);
    #pragma unroll
    for (int k = 0; k < 8; ++k) {
        const int f = t + k * 256;            // float4 index in tile, 0..2047
        const float4 pv = p4[f];
        const unsigned int sh = (f & 7) << 2;
        const unsigned int mN = (eM[f >> 3] >> sh) & 0xFu;
        const unsigned int eN = (eE[f >> 3] >> sh) & 0xFu;
        const float pj[4] = {pv.x, pv.y, pv.z, pv.w};
        #pragma unroll
        for (int j = 0; j < 4; ++j) {
            const unsigned int m = (mN >> j) & 1u;
            const unsigned int e = (eN >> j) & 1u;
            const float x = m ? pj[j] : 1.0f - pj[j];
            const float l = __log2f(x);
            s2A += l;
            s2E += e ? l : 0.f;
            s2M += m ? l : 0.f;
        }
    }

    // wave (64-lane) shuffle reduction
    #pragma unroll
    for (int off = 32; off; off >>= 1) {
        s2A += __shfl_down(s2A, off);
        s2E += __shfl_down(s2E, off);
        s2M += __shfl_down(s2M, off);
        cM  += __shfl_down(cM, off);
        cE  += __shfl_down(cE, off);
    }
    const int wave = t >> 6, lane = t & 63;
    if (lane == 0) {
        redf[wave * 3 + 0] = s2A;
        redf[wave * 3 + 1] = s2E;
        redf[wave * 3 + 2] = s2M;
        redc[wave * 2 + 0] = cM;
        redc[wave * 2 + 1] = cE;
    }
    __syncthreads();
    if (t == 0) {
        float tA = 0.f, tEg = 0.f, tMg = 0.f;
        unsigned int tM = 0, tEd = 0;
        #pragma unroll
        for (int wv = 0; wv < 4; ++wv) {
            tA  += redf[wv * 3 + 0];
            tEg += redf[wv * 3 + 1];
            tMg += redf[wv * 3 + 2];
            tM  += redc[wv * 2 + 0];
            tEd += redc[wv * 2 + 1];
        }
        Acc* a = &acc[blockIdx.x & (NBUCKET - 1)];   // 2 blocks/bucket
        atomicAdd(&a->s2A, (double)tA);
        atomicAdd(&a->s2E, (double)tEg);
        atomicAdd(&a->s2M, (double)tMg);
        atomicAdd(&a->cMask, tM);
        atomicAdd(&a->cEdge, tEd);
        __threadfence();                      // order bucket atomics before counter
        unsigned int old = atomicAdd(done, 1u);
        lastFlag = (old == (unsigned int)(gridDim.x - 1)) ? 1 : 0;
    }
    __syncthreads();

    // ---- fused finalize: the last block to arrive reduces the buckets ----
    if (lastFlag) {
        __threadfence();
        double sA = 0.0, sEg = 0.0, sMg = 0.0, nM = 0.0, nEd = 0.0;
        for (int idx = t; idx < NBUCKET; idx += 256) {
            // agent-scope loads: per-XCD L2s are not cross-coherent (G16)
            sA  += __hip_atomic_load(&acc[idx].s2A, __ATOMIC_RELAXED, __HIP_MEMORY_SCOPE_AGENT);
            sEg += __hip_atomic_load(&acc[idx].s2E, __ATOMIC_RELAXED, __HIP_MEMORY_SCOPE_AGENT);
            sMg += __hip_atomic_load(&acc[idx].s2M, __ATOMIC_RELAXED, __HIP_MEMORY_SCOPE_AGENT);
            nM  += (double)__hip_atomic_load(&acc[idx].cMask, __ATOMIC_RELAXED, __HIP_MEMORY_SCOPE_AGENT);
            nEd += (double)__hip_atomic_load(&acc[idx].cEdge, __ATOMIC_RELAXED, __HIP_MEMORY_SCOPE_AGENT);
        }
        #pragma unroll
        for (int off = 32; off; off >>= 1) {
            sA  += __shfl_down(sA, off);
            sEg += __shfl_down(sEg, off);
            sMg += __shfl_down(sMg, off);
            nM  += __shfl_down(nM, off);
            nEd += __shfl_down(nEd, off);
        }
        if (lane == 0) {
            redd[wave * 3 + 0] = sA;
            redd[wave * 3 + 1] = sEg;
            redd[wave * 3 + 2] = sMg;
            redn[wave * 2 + 0] = nM;
            redn[wave * 2 + 1] = nEd;
        }
        __syncthreads();
        if (t == 0) {
            double tA = 0, tEg = 0, tMg = 0, tM = 0, tEd = 0;
            #pragma unroll
            for (int wv = 0; wv < 4; ++wv) {
                tA  += redd[wv * 3 + 0];
                tEg += redd[wv * 3 + 1];
                tMg += redd[wv * 3 + 2];
                tM  += redn[wv * 2 + 0];
                tEd += redn[wv * 2 + 1];
            }
            double sE_bce = -LN2 * tMg;       // label==1 pixels
            double sEdge  = -LN2 * tEg;       // edge==1 pixels
            double sAll   = -LN2 * tA;        // all pixels
            double sB_bce = sEdge - sE_bce;   // boundary band
            double sT_bce = sAll - sEdge;     // texture
            double nBnd = tEd - tM;
            double nT   = NTOTAL - tEd;
            double wE = (1.0 - tM   / NTOTAL) * 1.0;
            double wB = (1.0 - nBnd / NTOTAL) * 0.8;
            double wT = (1.0 - nT   / NTOTAL) * 0.5;
            out[0] = (float)((wE * sE_bce + wB * sB_bce + wT * sT_bce) / NTOTAL);
        }
    }
}

extern "C" void kernel_launch(void* const* d_in, const int* in_sizes, int n_in,
                              void* d_out, int out_size, void* d_ws, size_t ws_size,
                              hipStream_t stream) {
    const float* pred  = (const float*)d_in[0];   // Pred, float32
    const int*   label = (const int*)d_in[1];     // label, int32
    float* out = (float*)d_out;

    char* ws = (char*)d_ws;
    Acc* acc = (Acc*)ws;
    unsigned int* maskbits = (unsigned int*)(ws + (size_t)NBUCKET * sizeof(Acc));
    unsigned int* done     = (unsigned int*)(ws + (size_t)NBUCKET * sizeof(Acc)
                                               + (size_t)NROWS * WPR * 4);

    k_pack<<<NROWS / 8, 256, 0, stream>>>(label, maskbits, acc, done);
    k_bce<<<NROWS / 8, 256, 0, stream>>>(pred, maskbits, acc, done, out);
}

// Round 2
// 150.768 us; speedup vs baseline: 1.4853x; 1.4853x over previous
//
#include <hip/hip_runtime.h>
#include <math.h>

// Problem constants (from reference setup_inputs): B=16, C=1, H=1024, W=1024
#define IMG_H 1024
#define IMG_W 1024
#define NB    16
#define NROWS (NB * IMG_H)        // 16384 flat rows
#define WPR   (IMG_W / 32)        // 32 u32 words per row
#define NTOTAL 16777216.0
#define NBUCKET 1024
#define LN2 0.6931471805599453

struct Acc {
    double s2A, s2E, s2M;         // sums of log2(pSel) over: all px, edge px, mask px
    unsigned int cMask, cEdge;    // counts of label==1 and edge==1
};                                 // 32 bytes = 8 dwords

// ---------------- Kernel 1: bitpack label only (no dilation) ----------------
// Each block: 8 consecutive flat rows (8192 px), 256 threads, int4 loads.
// Also zeroes the Acc buckets (blocks 0..NBUCKET-1), replacing a memset launch.
// Dilation is fully deferred to k_bce (separable OR: vertical then horizontal).
__global__ void k_pack(const int* __restrict__ label,
                       unsigned int* __restrict__ maskbits,
                       Acc* __restrict__ acc) {
    __shared__ unsigned int lm[256];          // 8 rows * 32 words
    const int t = threadIdx.x;
    const long rowBase = (long)blockIdx.x * 8;

    if (blockIdx.x < NBUCKET && t < 8)        // zero this block's bucket
        ((unsigned int*)&acc[blockIdx.x])[t] = 0u;

    // Bitpack: each thread loads 8 int4 (32 labels); nibble -> word via 3 shfl_xor.
    const int4* L = (const int4*)(label + rowBase * IMG_W);
    #pragma unroll
    for (int k = 0; k < 8; ++k) {
        const int fi = k * 256 + t;           // int4 index in tile, 0..2047
        const int4 v = L[fi];
        unsigned int wbits = ((unsigned int)(v.x & 1)
                           | ((unsigned int)(v.y & 1) << 1)
                           | ((unsigned int)(v.z & 1) << 2)
                           | ((unsigned int)(v.w & 1) << 3)) << ((t & 7) * 4);
        wbits |= __shfl_xor(wbits, 1);
        wbits |= __shfl_xor(wbits, 2);
        wbits |= __shfl_xor(wbits, 4);
        if ((t & 7) == 0) lm[fi >> 3] = wbits;
    }
    __syncthreads();
    maskbits[rowBase * WPR + t] = lm[t];      // coalesced 1 KiB/block
}

// ---------------- Kernel 2: dilate (V then H) + classified BCE --------------
// 2048 blocks x 256 threads; each block = 8 rows (8192 px), 32 px/thread.
__global__ void k_bce(const float* __restrict__ pred,
                      const unsigned int* __restrict__ maskbits,
                      Acc* __restrict__ acc) {
    __shared__ unsigned int vE[256];          // vertically-ORed words
    __shared__ unsigned int eE[256];          // final edge words (V+H dilated)
    __shared__ unsigned int eM[256];          // raw mask words (own rows)
    __shared__ float redf[12];                // 4 waves * 3 sums
    __shared__ unsigned int redc[8];          // 4 waves * 2 counts

    const int t  = threadIdx.x;
    const int R0 = blockIdx.x * 8;            // first flat row of tile
    const int b  = R0 >> 10;                  // image index
    const int i0 = R0 & 1023;                 // first row within image
    const int g = t >> 5, w = t & 31;         // row-in-tile, word

    // Vertical 15-tap OR on raw mask bits: one word per thread.
    {
        const int i = i0 + g;
        int lo = i - 7; if (lo < 0) lo = 0;
        int hi = i + 7; if (hi > 1023) hi = 1023;
        const unsigned int* base = maskbits + ((long)b << 10) * WPR + w;
        unsigned int e = 0u;
        for (int ri = lo; ri <= hi; ++ri) e |= base[(long)ri * WPR];
        vE[t] = e;
        eM[t] = base[(long)i * WPR];          // own-row raw mask (L1/L2 hit)
    }
    __syncthreads();

    // Horizontal 15-tap OR within the row using LDS neighbors.
    unsigned int cE;
    {
        unsigned int prev = w        ? vE[t - 1] : 0u;
        unsigned int cur  =            vE[t];
        unsigned int next = (w < 31) ? vE[t + 1] : 0u;
        unsigned long long Wn = (((unsigned long long)prev) >> 16)
                              | (((unsigned long long)cur)  << 16)
                              | (((unsigned long long)next) << 48);
        unsigned long long a = Wn;
        #pragma unroll
        for (int d = 1; d <= 7; ++d) a |= (Wn >> d) | (Wn << d);
        unsigned int ew = (unsigned int)(a >> 16);
        eE[t] = ew;
        cE = __popc(ew);
    }
    unsigned int cM = __popc(eM[t]);
    __syncthreads();

    // 32 px/thread via 8 coalesced float4 loads; accumulate log2 sums.
    float s2A = 0.f, s2E = 0.f, s2M = 0.f;
    const float4* p4 = (const float4*)(pred + (long)R0 * IMG_W);
    #pragma unroll
    for (int k = 0; k < 8; ++k) {
        const int f = t + k * 256;            // float4 index in tile, 0..2047
        const float4 pv = p4[f];
        const unsigned int sh = (f & 7) << 2;
        const unsigned int mN = (eM[f >> 3] >> sh) & 0xFu;
        const unsigned int eN = (eE[f >> 3] >> sh) & 0xFu;
        const float pj[4] = {pv.x, pv.y, pv.z, pv.w};
        #pragma unroll
        for (int j = 0; j < 4; ++j) {
            const unsigned int m = (mN >> j) & 1u;
            const unsigned int e = (eN >> j) & 1u;
            const float x = m ? pj[j] : 1.0f - pj[j];
            const float l = __log2f(x);
            s2A += l;
            s2E += e ? l : 0.f;
            s2M += m ? l : 0.f;
        }
    }

    // wave (64-lane) shuffle reduction
    #pragma unroll
    for (int off = 32; off; off >>= 1) {
        s2A += __shfl_down(s2A, off);
        s2E += __shfl_down(s2E, off);
        s2M += __shfl_down(s2M, off);
        cM  += __shfl_down(cM, off);
        cE  += __shfl_down(cE, off);
    }
    const int wave = t >> 6, lane = t & 63;
    if (lane == 0) {
        redf[wave * 3 + 0] = s2A;
        redf[wave * 3 + 1] = s2E;
        redf[wave * 3 + 2] = s2M;
        redc[wave * 2 + 0] = cM;
        redc[wave * 2 + 1] = cE;
    }
    __syncthreads();
    if (t == 0) {
        float tA = 0.f, tEg = 0.f, tMg = 0.f;
        unsigned int tM = 0, tEd = 0;
        #pragma unroll
        for (int wv = 0; wv < 4; ++wv) {
            tA  += redf[wv * 3 + 0];
            tEg += redf[wv * 3 + 1];
            tMg += redf[wv * 3 + 2];
            tM  += redc[wv * 2 + 0];
            tEd += redc[wv * 2 + 1];
        }
        Acc* a = &acc[blockIdx.x & (NBUCKET - 1)];   // 2 blocks/bucket
        atomicAdd(&a->s2A, (double)tA);
        atomicAdd(&a->s2E, (double)tEg);
        atomicAdd(&a->s2M, (double)tMg);
        atomicAdd(&a->cMask, tM);
        atomicAdd(&a->cEdge, tEd);
    }
}

// ---------------- Kernel 3: reduce buckets + finalize scalar ----------------
__global__ void k_final(const Acc* __restrict__ acc, float* __restrict__ out) {
    __shared__ double redd[12];
    __shared__ double redn[8];
    const int t = threadIdx.x;                // 256 threads
    double sA = 0.0, sEg = 0.0, sMg = 0.0, nM = 0.0, nEd = 0.0;
    for (int idx = t; idx < NBUCKET; idx += 256) {
        sA  += acc[idx].s2A;  sEg += acc[idx].s2E;  sMg += acc[idx].s2M;
        nM  += (double)acc[idx].cMask;  nEd += (double)acc[idx].cEdge;
    }
    #pragma unroll
    for (int off = 32; off; off >>= 1) {
        sA  += __shfl_down(sA, off);
        sEg += __shfl_down(sEg, off);
        sMg += __shfl_down(sMg, off);
        nM  += __shfl_down(nM, off);
        nEd += __shfl_down(nEd, off);
    }
    const int wave = t >> 6, lane = t & 63;
    if (lane == 0) {
        redd[wave * 3 + 0] = sA;
        redd[wave * 3 + 1] = sEg;
        redd[wave * 3 + 2] = sMg;
        redn[wave * 2 + 0] = nM;
        redn[wave * 2 + 1] = nEd;
    }
    __syncthreads();
    if (t == 0) {
        double tA = 0, tEg = 0, tMg = 0, tM = 0, tEd = 0;
        #pragma unroll
        for (int wv = 0; wv < 4; ++wv) {
            tA  += redd[wv * 3 + 0];
            tEg += redd[wv * 3 + 1];
            tMg += redd[wv * 3 + 2];
            tM  += redn[wv * 2 + 0];
            tEd += redn[wv * 2 + 1];
        }
        double sE_bce = -LN2 * tMg;           // label==1 pixels
        double sEdge  = -LN2 * tEg;           // edge==1 pixels
        double sAll   = -LN2 * tA;            // all pixels
        double sB_bce = sEdge - sE_bce;       // boundary band
        double sT_bce = sAll - sEdge;         // texture
        double nBnd = tEd - tM;
        double nT   = NTOTAL - tEd;
        double wE = (1.0 - tM   / NTOTAL) * 1.0;
        double wB = (1.0 - nBnd / NTOTAL) * 0.8;
        double wT = (1.0 - nT   / NTOTAL) * 0.5;
        out[0] = (float)((wE * sE_bce + wB * sB_bce + wT * sT_bce) / NTOTAL);
    }
}

extern "C" void kernel_launch(void* const* d_in, const int* in_sizes, int n_in,
                              void* d_out, int out_size, void* d_ws, size_t ws_size,
                              hipStream_t stream) {
    const float* pred  = (const float*)d_in[0];   // Pred, float32
    const int*   label = (const int*)d_in[1];     // label, int32
    float* out = (float*)d_out;

    char* ws = (char*)d_ws;
    Acc* acc = (Acc*)ws;
    unsigned int* maskbits = (unsigned int*)(ws + (size_t)NBUCKET * sizeof(Acc));

    k_pack<<<NROWS / 8, 256, 0, stream>>>(label, maskbits, acc);
    k_bce<<<NROWS / 8, 256, 0, stream>>>(pred, maskbits, acc);
    k_final<<<1, 256, 0, stream>>>(acc, out);
}